// Round 3
// baseline (7907.380 us; speedup 1.0000x reference)
//
#include <hip/hip_runtime.h>
#include <math.h>

// Problem constants (match reference)
#define NA 50000
#define NP 100000
#define NTOT 150000
#define EW 400000
#define ER 400000
#define EC 800000

static inline unsigned cdiv(unsigned a, unsigned b){ return (a+b-1)/b; }

__device__ __forceinline__ float gelu_f(float x){
  return x * 0.5f * (1.0f + erff(x * 0.70710678118654752440f));
}

// ---------------------------------------------------------------------------
// zero-fill helpers (avoid hipMemsetAsync entirely)
// ---------------------------------------------------------------------------
__global__ void zero_ints(int* __restrict__ p, int n){
  int i = blockIdx.x*blockDim.x + threadIdx.x;
  if (i < n) p[i] = 0;
}
__global__ void zero_floats(float* __restrict__ p, int n){
  int i = blockIdx.x*blockDim.x + threadIdx.x;
  if (i < n) p[i] = 0.f;
}
__global__ void zero_doubles(double* __restrict__ p, int n){
  int i = blockIdx.x*blockDim.x + threadIdx.x;
  if (i < n) p[i] = 0.0;
}

// ---------------------------------------------------------------------------
// GEMM: C = epilogue(A[M,128] @ W[128,N] + bias[N])
// MODE 0: relu, store C0[row*128+col]                 (N==128)
// MODE 1: kqv split: col<128 -> C0(k), <256 -> C1(q), else C2(v)  (N==384)
// MODE 2: gelu applied to A on load; h = sk*val + (1-sk)*xres; store C0 (N==128)
// ---------------------------------------------------------------------------
template<int MODE>
__global__ __launch_bounds__(256) void gemm_k128(
    const float* __restrict__ A, const float* __restrict__ W,
    const float* __restrict__ bias, int M, int N,
    float* __restrict__ C0, float* __restrict__ C1, float* __restrict__ C2,
    const float* __restrict__ xres, const float* __restrict__ skipp)
{
  __shared__ float As[32][64];   // [k][row] transposed A tile
  __shared__ float Bs[32][64];   // [k][col]
  const int tid = threadIdx.x;
  const int m0 = blockIdx.x*64, n0 = blockIdx.y*64;
  const int tx = tid & 15, ty = tid >> 4;
  const int ar = tid >> 2, ak0 = (tid & 3)*8;   // A stage: 4 thr/row, 8 floats each
  const int bk = tid >> 4, bc = (tid & 15)*4;   // B stage
  float acc[4][4] = {};
  const int grow_a = m0 + ar;
  const bool aok = grow_a < M;
  const float* aptr = A + (size_t)grow_a*128 + ak0;

  for (int kc = 0; kc < 128; kc += 32) {
    float a[8];
    if (aok) {
      float4 t0 = *(const float4*)(aptr + kc);
      float4 t1 = *(const float4*)(aptr + kc + 4);
      a[0]=t0.x;a[1]=t0.y;a[2]=t0.z;a[3]=t0.w;
      a[4]=t1.x;a[5]=t1.y;a[6]=t1.z;a[7]=t1.w;
      if (MODE==2) {
        #pragma unroll
        for (int u=0;u<8;++u) a[u] = gelu_f(a[u]);
      }
    } else {
      #pragma unroll
      for (int u=0;u<8;++u) a[u]=0.f;
    }
    float4 b0 = *(const float4*)(W + (size_t)(kc+bk)*N + n0 + bc);
    float4 b1 = *(const float4*)(W + (size_t)(kc+16+bk)*N + n0 + bc);
    __syncthreads();   // previous iter's LDS reads done before overwrite
    #pragma unroll
    for (int u=0;u<8;++u) As[ak0+u][ar] = a[u];
    *(float4*)&Bs[bk][bc]    = b0;
    *(float4*)&Bs[bk+16][bc] = b1;
    __syncthreads();
    #pragma unroll
    for (int k=0;k<32;++k) {
      float4 av = *(const float4*)&As[k][ty*4];
      float4 bv = *(const float4*)&Bs[k][tx*4];
      float aa[4] = {av.x,av.y,av.z,av.w};
      float bb[4] = {bv.x,bv.y,bv.z,bv.w};
      #pragma unroll
      for (int i=0;i<4;++i)
        #pragma unroll
        for (int j=0;j<4;++j)
          acc[i][j] += aa[i]*bb[j];
    }
  }

  float sk = 0.f;
  if (MODE==2) sk = 1.f/(1.f + expf(-*skipp));

  #pragma unroll
  for (int i=0;i<4;++i) {
    int grow = m0 + ty*4 + i;
    if (grow >= M) continue;
    #pragma unroll
    for (int j=0;j<4;++j) {
      int gc = n0 + tx*4 + j;
      float val = acc[i][j] + bias[gc];
      if (MODE==0) {
        C0[(size_t)grow*128 + gc] = fmaxf(val, 0.f);
      } else if (MODE==1) {
        int sub = gc >> 7, cc = gc & 127;
        float* p = (sub==0)?C0:((sub==1)?C1:C2);
        p[(size_t)grow*128 + cc] = val;
      } else {
        float hh = sk*val + (1.f-sk)*xres[(size_t)grow*128 + gc];
        C0[(size_t)grow*128 + gc] = hh;
      }
    }
  }
}

// ---------------------------------------------------------------------------
// CSR build helpers
// ---------------------------------------------------------------------------
__global__ void hist_kernel(const int* __restrict__ dst, int E, int* __restrict__ deg){
  int i = blockIdx.x*blockDim.x + threadIdx.x;
  if (i < E) atomicAdd(&deg[dst[i]], 1);
}

// single-block exclusive scan (1024 threads), also fills cursor copy
__global__ __launch_bounds__(1024) void scan_kernel(const int* __restrict__ deg,
                                                    int* __restrict__ indptr,
                                                    int* __restrict__ cursor, int n){
  __shared__ int buf[1024];
  __shared__ int carry_s;
  int tid = threadIdx.x;
  if (tid == 0) carry_s = 0;
  __syncthreads();
  for (int base = 0; base < n; base += 1024) {
    int i = base + tid;
    int x = (i < n) ? deg[i] : 0;
    buf[tid] = x;
    __syncthreads();
    for (int off = 1; off < 1024; off <<= 1) {
      int t = buf[tid];
      if (tid >= off) t += buf[tid-off];
      __syncthreads();
      buf[tid] = t;
      __syncthreads();
    }
    int incl = buf[tid];
    int excl = incl - x;
    int c = carry_s;
    if (i < n) { indptr[i] = c + excl; cursor[i] = c + excl; }
    int total = buf[1023];
    __syncthreads();
    if (tid == 0) carry_s = c + total;
    __syncthreads();
  }
  if (tid == 0) indptr[n] = carry_s;
}

__global__ void scatter_kernel(const int* __restrict__ src, const int* __restrict__ dst,
                               int E, int gsrc_off, int slot,
                               int* __restrict__ cursor, int* __restrict__ edges){
  int i = blockIdx.x*blockDim.x + threadIdx.x;
  if (i < E) {
    int d = dst[i];
    int pos = atomicAdd(&cursor[d], 1);
    edges[pos] = (src[i] + gsrc_off) | (slot << 20);
  }
}

// ---------------------------------------------------------------------------
// Edge attention + aggregation. One wave (64 lanes) per destination node.
// lane -> channels (2*lane, 2*lane+1); head h = lane>>3; within-head dims
// d = 2*(lane&7), +1. Online softmax per head; per-slot (edge-type) v-space
// accumulators; A_v applied once at the end.
// NOTE: agg may alias qb — each wave reads only its OWN node's q row (at
// start) and writes only its own agg row (at end); no cross-node q reads.
// ---------------------------------------------------------------------------
template<int NSLOT>
__global__ __launch_bounds__(256) void edge_attn(
    const float* __restrict__ qb, const float* __restrict__ kb, const float* __restrict__ vb,
    const int* __restrict__ indptr, const int* __restrict__ edges,
    const float* __restrict__ akl, const float* __restrict__ avl, const float* __restrict__ prl,
    float* __restrict__ agg, int n_nodes, int row_off, int et0, int et1)
{
  __shared__ float AkL[NSLOT*2048];
  __shared__ float AvL[NSLOT*2048];
  const int tid = threadIdx.x;
  int etg[2] = {et0, et1};
  for (int i = tid; i < NSLOT*2048; i += 256) {
    int s = i >> 11, o = i & 2047;
    AkL[i] = akl[etg[s]*2048 + o];
    AvL[i] = avl[etg[s]*2048 + o];
  }
  __syncthreads();

  int wid = blockIdx.x*4 + (tid >> 6);
  if (wid >= n_nodes) return;
  const int lane = tid & 63;
  const int h = lane >> 3;
  const int e2 = (lane & 7)*2;
  const size_t node = (size_t)(row_off + wid);

  float2 q2 = *(const float2*)(qb + node*128 + lane*2);

  // qA per slot (this lane holds dims d=e2, e2+1)
  float2 qa[NSLOT];
  #pragma unroll
  for (int s = 0; s < NSLOT; ++s) {
    const float* Ab = AkL + s*2048 + h*256;   // [d][e] 16x16
    float ax = 0.f, ay = 0.f;
    #pragma unroll
    for (int j = 0; j < 8; ++j) {
      float qx = __shfl(q2.x, (h<<3)+j, 64);  // q[h, 2j]
      float qy = __shfl(q2.y, (h<<3)+j, 64);  // q[h, 2j+1]
      ax += Ab[e2*16     + 2*j]*qx + Ab[e2*16     + 2*j+1]*qy;
      ay += Ab[(e2+1)*16 + 2*j]*qx + Ab[(e2+1)*16 + 2*j+1]*qy;
    }
    float pr = prl[etg[s]*8 + h] * 0.25f;     // p_rel * 1/sqrt(D)
    qa[s] = make_float2(ax*pr, ay*pr);
  }

  float m = -INFINITY, denom = 0.f;
  float2 acc[NSLOT];
  #pragma unroll
  for (int s = 0; s < NSLOT; ++s) acc[s] = make_float2(0.f, 0.f);

  const int beg = indptr[wid], end = indptr[wid+1];
  for (int e = beg; e < end; ++e) {
    int meta = edges[e];
    int gsrc = meta & 0xFFFFF;
    int s = meta >> 20;
    float2 kk = *(const float2*)(kb + (size_t)gsrc*128 + lane*2);
    float2 qs = (NSLOT==2 && s) ? qa[NSLOT-1] : qa[0];
    float part = qs.x*kk.x + qs.y*kk.y;
    part += __shfl_xor(part, 1, 64);
    part += __shfl_xor(part, 2, 64);
    part += __shfl_xor(part, 4, 64);          // alpha for this head
    float mn = fmaxf(m, part);
    float f = expf(m - mn);                   // m=-inf first iter -> f=0
    float w = expf(part - mn);
    denom = denom*f + w;
    float2 vv = *(const float2*)(vb + (size_t)gsrc*128 + lane*2);
    #pragma unroll
    for (int ss = 0; ss < NSLOT; ++ss) { acc[ss].x *= f; acc[ss].y *= f; }
    if (NSLOT==2 && s) { acc[NSLOT-1].x += w*vv.x; acc[NSLOT-1].y += w*vv.y; }
    else               { acc[0].x += w*vv.x; acc[0].y += w*vv.y; }
    m = mn;
  }

  // apply A_v per slot and sum; lane outputs dims e=e2,e2+1
  float ox = 0.f, oy = 0.f;
  #pragma unroll
  for (int s = 0; s < NSLOT; ++s) {
    const float* Ab = AvL + s*2048 + h*256;   // [d][e]
    #pragma unroll
    for (int j = 0; j < 8; ++j) {
      float px = __shfl(acc[s].x, (h<<3)+j, 64);  // acc[h, 2j]
      float py = __shfl(acc[s].y, (h<<3)+j, 64);  // acc[h, 2j+1]
      ox += px*Ab[(2*j)*16 + e2]   + py*Ab[(2*j+1)*16 + e2];
      oy += px*Ab[(2*j)*16 + e2+1] + py*Ab[(2*j+1)*16 + e2+1];
    }
  }
  float dinv = 1.f/(denom + 1e-16f);
  float2 o = make_float2(ox*dinv, oy*dinv);
  *(float2*)(agg + node*128 + lane*2) = o;
}

// ---------------------------------------------------------------------------
// BatchNorm: stats (fp64 atomics) then apply
// ---------------------------------------------------------------------------
__global__ __launch_bounds__(256) void bn_stats(const float* __restrict__ h, int n,
                                                double* __restrict__ stats){
  const int c = threadIdx.x & 127, half = threadIdx.x >> 7;
  float s = 0.f, s2 = 0.f;
  for (int r = blockIdx.x*2 + half; r < n; r += gridDim.x*2) {
    float x = h[(size_t)r*128 + c];
    s += x; s2 += x*x;
  }
  __shared__ float sh[2][128], sh2[2][128];
  sh[half][c] = s; sh2[half][c] = s2;
  __syncthreads();
  if (half == 0) {
    double S  = (double)s  + (double)sh[1][c];
    double S2 = (double)s2 + (double)sh2[1][c];
    atomicAdd(&stats[c], S);
    atomicAdd(&stats[128+c], S2);
  }
}

__global__ __launch_bounds__(256) void bn_apply(const float* __restrict__ h,
                                                const double* __restrict__ stats,
                                                const float* __restrict__ gamma,
                                                const float* __restrict__ beta,
                                                float* __restrict__ out, int n){
  const int c = threadIdx.x & 127;
  double inv_n = 1.0/(double)n;
  double mu = stats[c]*inv_n;
  double var = stats[128+c]*inv_n - mu*mu;
  float scale = (float)((double)gamma[c] / sqrt(var + 1e-5));
  float shift = (float)((double)beta[c] - mu*(double)scale);
  for (int r = blockIdx.x*2 + (threadIdx.x>>7); r < n; r += gridDim.x*2) {
    out[(size_t)r*128 + c] = h[(size_t)r*128 + c]*scale + shift;
  }
}

// ---------------------------------------------------------------------------
extern "C" void kernel_launch(void* const* d_in, const int* in_sizes, int n_in,
                              void* d_out, int out_size, void* d_ws, size_t ws_size,
                              hipStream_t stream)
{
  const float* x_author = (const float*)d_in[0];
  const float* x_paper  = (const float*)d_in[1];
  const int* writes_src = (const int*)d_in[2];
  const int* writes_dst = (const int*)d_in[3];
  const int* rev_src    = (const int*)d_in[4];
  const int* rev_dst    = (const int*)d_in[5];
  const int* cites_src  = (const int*)d_in[6];
  const int* cites_dst  = (const int*)d_in[7];
  const float* linA_W = (const float*)d_in[8];
  const float* linA_b = (const float*)d_in[9];
  const float* linP_W = (const float*)d_in[10];
  const float* linP_b = (const float*)d_in[11];
  const float* kqv_W  = (const float*)d_in[12];
  const float* kqv_b  = (const float*)d_in[13];
  const float* a_k    = (const float*)d_in[14];
  const float* a_v    = (const float*)d_in[15];
  const float* p_rel  = (const float*)d_in[16];
  const float* out_W  = (const float*)d_in[17];
  const float* out_b  = (const float*)d_in[18];
  const float* skip   = (const float*)d_in[19];
  const float* bn_g   = (const float*)d_in[20];
  const float* bn_b   = (const float*)d_in[21];

  const size_t FEAT = (size_t)NTOT*128;   // 19,200,000 floats

  // x lives in d_out (author rows then paper rows), fully rewritten each call.
  // Workspace: stats(256 dbl) | qb(=agg) kb(=h) vb | CSR ints.
  float* x = (float*)d_out;
  double* stats = (double*)d_ws;
  float* fbase = (float*)((char*)d_ws + 2048);
  float* qb  = fbase;            // q, then agg (in-place), per layer
  float* kb  = qb  + FEAT;       // k, then h (out-proj result), per layer
  float* vb  = kb  + FEAT;       // v
  int* ibase = (int*)(vb + FEAT);
  int* indptrA = ibase;               // NA+1
  int* cursorA = indptrA + (NA+1);    // NA
  int* degA    = cursorA + NA;        // NA
  int* indptrP = degA + NA;           // NP+1
  int* cursorP = indptrP + (NP+1);    // NP
  int* degP    = cursorP + NP;        // NP
  int* edgesA  = degP + NP;           // ER
  int* edgesP  = edgesA + ER;         // EW+EC

  size_t need = 2048 + FEAT*3*sizeof(float)
              + (size_t)((NA+1)+NA+NA+(NP+1)+NP+NP+ER+EW+EC)*sizeof(int);
  if (ws_size < need) {   // clean fail: zero output so the mismatch is diagnosable
    zero_floats<<<cdiv(out_size,256),256,0,stream>>>((float*)d_out, out_size);
    return;
  }

  // ---- CSR build (rebuilt every call; no static state) ----
  zero_ints<<<cdiv(NA,256),256,0,stream>>>(degA, NA);
  zero_ints<<<cdiv(NP,256),256,0,stream>>>(degP, NP);
  hist_kernel<<<cdiv(ER,256),256,0,stream>>>(rev_dst, ER, degA);
  hist_kernel<<<cdiv(EW,256),256,0,stream>>>(writes_dst, EW, degP);
  hist_kernel<<<cdiv(EC,256),256,0,stream>>>(cites_dst, EC, degP);
  scan_kernel<<<1,1024,0,stream>>>(degA, indptrA, cursorA, NA);
  scan_kernel<<<1,1024,0,stream>>>(degP, indptrP, cursorP, NP);
  // dest author: rev edges (papers as src, global row +NA), slot 0 (et=1)
  scatter_kernel<<<cdiv(ER,256),256,0,stream>>>(rev_src, rev_dst, ER, NA, 0, cursorA, edgesA);
  // dest paper: writes (authors, +0), slot 0 (et=0); cites (papers, +NA), slot 1 (et=2)
  scatter_kernel<<<cdiv(EW,256),256,0,stream>>>(writes_src, writes_dst, EW, 0, 0, cursorP, edgesP);
  scatter_kernel<<<cdiv(EC,256),256,0,stream>>>(cites_src, cites_dst, EC, NA, 1, cursorP, edgesP);

  // ---- input projections + relu ----
  gemm_k128<0><<<dim3(cdiv(NA,64),2),256,0,stream>>>(x_author, linA_W, linA_b, NA, 128,
                                                     x, nullptr, nullptr, nullptr, nullptr);
  gemm_k128<0><<<dim3(cdiv(NP,64),2),256,0,stream>>>(x_paper, linP_W, linP_b, NP, 128,
                                                     x + (size_t)NA*128, nullptr, nullptr, nullptr, nullptr);

  for (int l = 0; l < 2; ++l) {
    // KQV per node type
    for (int t = 0; t < 2; ++t) {
      size_t off = t ? (size_t)NA*128 : 0;
      int M = t ? NP : NA;
      const float* Wp = kqv_W + (size_t)(l*2+t)*128*384;
      const float* bp = kqv_b + (size_t)(l*2+t)*384;
      gemm_k128<1><<<dim3(cdiv(M,64),6),256,0,stream>>>(x + off, Wp, bp, M, 384,
                                                        kb + off, qb + off, vb + off,
                                                        nullptr, nullptr);
    }
    const float* akl = a_k + (size_t)l*3*2048;
    const float* avl = a_v + (size_t)l*3*2048;
    const float* prl = p_rel + (size_t)l*24;
    // agg aliases qb (safe: per-node q read precedes per-node agg write)
    edge_attn<1><<<NA/4,256,0,stream>>>(qb, kb, vb, indptrA, edgesA, akl, avl, prl,
                                        qb, NA, 0, 1, -1);
    edge_attn<2><<<NP/4,256,0,stream>>>(qb, kb, vb, indptrP, edgesP, akl, avl, prl,
                                        qb, NP, NA, 0, 2);

    // out-proj + skip + BN per node type (agg=qb read; h written to kb — k dead)
    for (int t = 0; t < 2; ++t) {
      size_t off = t ? (size_t)NA*128 : 0;
      int M = t ? NP : NA;
      float* hbuf = kb + off;
      const float* Wp = out_W + (size_t)(l*2+t)*128*128;
      const float* bp = out_b + (size_t)(l*2+t)*128;
      gemm_k128<2><<<dim3(cdiv(M,64),2),256,0,stream>>>(qb + off, Wp, bp, M, 128,
                                                        hbuf, nullptr, nullptr,
                                                        x + off, skip + (l*2+t));
      zero_doubles<<<1,256,0,stream>>>(stats, 256);
      bn_stats<<<512,256,0,stream>>>(hbuf, M, stats);
      bn_apply<<<1024,256,0,stream>>>(hbuf, stats, bn_g + l*128, bn_b + l*128, x + off, M);
    }
  }
}

// Round 4
// 2351.342 us; speedup vs baseline: 3.3629x; 3.3629x over previous
//
#include <hip/hip_runtime.h>
#include <math.h>

// Problem constants (match reference)
#define NA 50000
#define NP 100000
#define NTOT 150000
#define EW 400000
#define ER 400000
#define EC 800000

typedef _Float16 f16;
typedef _Float16 f16x8 __attribute__((ext_vector_type(8)));
typedef _Float16 f16x2 __attribute__((ext_vector_type(2)));
typedef float f32x4 __attribute__((ext_vector_type(4)));

static inline unsigned cdiv(unsigned a, unsigned b){ return (a+b-1)/b; }

__device__ __forceinline__ float gelu_f(float x){
  return x * 0.5f * (1.0f + erff(x * 0.70710678118654752440f));
}

// ---------------------------------------------------------------------------
// zero-fill helpers (avoid hipMemsetAsync)
// ---------------------------------------------------------------------------
__global__ void zero_ints(int* __restrict__ p, int n){
  int i = blockIdx.x*blockDim.x + threadIdx.x;
  if (i < n) p[i] = 0;
}
__global__ void zero_floats(float* __restrict__ p, int n){
  int i = blockIdx.x*blockDim.x + threadIdx.x;
  if (i < n) p[i] = 0.f;
}
__global__ void zero_doubles(double* __restrict__ p, int n){
  int i = blockIdx.x*blockDim.x + threadIdx.x;
  if (i < n) p[i] = 0.0;
}

// convert fp32 W[128][N] -> fp16 Wt[N][128] (transposed, MFMA-friendly)
__global__ void prep_w(const float* __restrict__ W, f16* __restrict__ Wt, int N){
  int i = blockIdx.x*blockDim.x + threadIdx.x;
  if (i < 128*N){ int k = i / N, n = i - k*N; Wt[n*128 + k] = (f16)W[i]; }
}

// ---------------------------------------------------------------------------
// fp16 MFMA GEMM: C = epilogue(A[M,128] @ W[128,N] + bias), K=128 single stage.
// BM=128, BN=64, 256 threads (4 waves); wave w does rows [w*32,w*32+32) x 64 cols
// via 2x4 fragments of v_mfma_f32_16x16x32_f16 (4 k-steps each), fp32 accum.
// A/B lane layout: lane l holds {row|col}=l&15, k=(l>>4)*8+j (j=0..7).
// C/D layout: col=l&15, row=(l>>4)*4+reg  [HW-verified mapping].
// MODE 0: A fp32 src, relu -> H0 (f16)
// MODE 1: A f16 src, kqv col-split -> H0=k(f16), H1=q(f16), F2=v(f32)
// MODE 2: A f16 src + gelu on load; h = sk*val+(1-sk)*xres -> H0 (f16)
// ---------------------------------------------------------------------------
template<int MODE>
__global__ __launch_bounds__(256) void gemm_mfma(
    const void* __restrict__ Av, const f16* __restrict__ Wt,
    const float* __restrict__ bias, int M, int N,
    f16* __restrict__ H0, f16* __restrict__ H1, float* __restrict__ F2,
    const f16* __restrict__ xres, const float* __restrict__ skipp)
{
  __shared__ f16 As[128][136];   // +8 pad: 2-way-max bank aliasing on b128 reads
  __shared__ f16 Bs[64][136];    // stored [col][k]
  const int tid = threadIdx.x;
  const int m0 = blockIdx.x*128, n0 = blockIdx.y*64;

  // --- stage A: 4 threads/row (32 elems each), 2 passes of 64 rows ---
  #pragma unroll
  for (int p = 0; p < 2; ++p) {
    int r = (tid >> 2) + p*64;
    int seg = (tid & 3)*32;
    int grow = m0 + r;
    f16* dst = &As[r][seg];
    if (MODE == 0) {
      const float* Ap = (const float*)Av + (size_t)grow*128 + seg;
      if (grow < M) {
        #pragma unroll
        for (int u = 0; u < 8; ++u) {
          float4 t = *(const float4*)(Ap + u*4);
          dst[u*4+0]=(f16)t.x; dst[u*4+1]=(f16)t.y;
          dst[u*4+2]=(f16)t.z; dst[u*4+3]=(f16)t.w;
        }
      } else {
        #pragma unroll
        for (int u = 0; u < 32; ++u) dst[u] = (f16)0.f;
      }
    } else {
      const f16* Ap = (const f16*)Av + (size_t)grow*128 + seg;
      if (grow < M) {
        #pragma unroll
        for (int u = 0; u < 4; ++u) {
          f16x8 t = *(const f16x8*)(Ap + u*8);
          if (MODE == 2) {
            #pragma unroll
            for (int j = 0; j < 8; ++j) t[j] = (f16)gelu_f((float)t[j]);
          }
          *(f16x8*)(dst + u*8) = t;
        }
      } else {
        #pragma unroll
        for (int u = 0; u < 32; ++u) dst[u] = (f16)0.f;
      }
    }
  }
  // --- stage B: 4 threads/col, Wt already [N][128] f16 ---
  {
    int c = tid >> 2, kseg = (tid & 3)*32;
    const f16* Bp = Wt + (size_t)(n0 + c)*128 + kseg;
    f16* dst = &Bs[c][kseg];
    #pragma unroll
    for (int u = 0; u < 4; ++u)
      *(f16x8*)(dst + u*8) = *(const f16x8*)(Bp + u*8);
  }
  __syncthreads();

  const int w = tid >> 6, lane = tid & 63;
  const int fr = lane & 15, fq = lane >> 4;
  f16x8 af[2][4];
  #pragma unroll
  for (int mi = 0; mi < 2; ++mi)
    #pragma unroll
    for (int kk = 0; kk < 4; ++kk)
      af[mi][kk] = *(const f16x8*)&As[w*32 + mi*16 + fr][kk*32 + fq*8];

  f32x4 acc[2][4];
  #pragma unroll
  for (int mi = 0; mi < 2; ++mi)
    #pragma unroll
    for (int ni = 0; ni < 4; ++ni)
      acc[mi][ni] = (f32x4){0.f,0.f,0.f,0.f};

  #pragma unroll
  for (int ni = 0; ni < 4; ++ni) {
    #pragma unroll
    for (int kk = 0; kk < 4; ++kk) {
      f16x8 bf = *(const f16x8*)&Bs[ni*16 + fr][kk*32 + fq*8];
      acc[0][ni] = __builtin_amdgcn_mfma_f32_16x16x32_f16(af[0][kk], bf, acc[0][ni], 0, 0, 0);
      acc[1][ni] = __builtin_amdgcn_mfma_f32_16x16x32_f16(af[1][kk], bf, acc[1][ni], 0, 0, 0);
    }
  }

  float sk = 0.f;
  if (MODE == 2) sk = 1.f/(1.f + expf(-*skipp));

  #pragma unroll
  for (int mi = 0; mi < 2; ++mi) {
    #pragma unroll
    for (int j = 0; j < 4; ++j) {
      int grow = m0 + w*32 + mi*16 + fq*4 + j;
      if (grow >= M) continue;
      #pragma unroll
      for (int ni = 0; ni < 4; ++ni) {
        int gc = n0 + ni*16 + fr;
        float val = acc[mi][ni][j] + bias[gc];
        if (MODE == 0) {
          H0[(size_t)grow*128 + gc] = (f16)fmaxf(val, 0.f);
        } else if (MODE == 1) {
          int sub = gc >> 7, cc = gc & 127;
          if (sub == 0)      H0[(size_t)grow*128 + cc] = (f16)val;
          else if (sub == 1) H1[(size_t)grow*128 + cc] = (f16)val;
          else               F2[(size_t)grow*128 + cc] = val;
        } else {
          float hh = sk*val + (1.f-sk)*(float)xres[(size_t)grow*128 + gc];
          H0[(size_t)grow*128 + gc] = (f16)hh;
        }
      }
    }
  }
}

// ---------------------------------------------------------------------------
// CSR build helpers
// ---------------------------------------------------------------------------
__global__ void hist_kernel(const int* __restrict__ dst, int E, int* __restrict__ deg){
  int i = blockIdx.x*blockDim.x + threadIdx.x;
  if (i < E) atomicAdd(&deg[dst[i]], 1);
}

__global__ __launch_bounds__(1024) void scan_kernel(const int* __restrict__ deg,
                                                    int* __restrict__ indptr,
                                                    int* __restrict__ cursor, int n){
  __shared__ int buf[1024];
  __shared__ int carry_s;
  int tid = threadIdx.x;
  if (tid == 0) carry_s = 0;
  __syncthreads();
  for (int base = 0; base < n; base += 1024) {
    int i = base + tid;
    int x = (i < n) ? deg[i] : 0;
    buf[tid] = x;
    __syncthreads();
    for (int off = 1; off < 1024; off <<= 1) {
      int t = buf[tid];
      if (tid >= off) t += buf[tid-off];
      __syncthreads();
      buf[tid] = t;
      __syncthreads();
    }
    int incl = buf[tid];
    int excl = incl - x;
    int c = carry_s;
    if (i < n) { indptr[i] = c + excl; cursor[i] = c + excl; }
    int total = buf[1023];
    __syncthreads();
    if (tid == 0) carry_s = c + total;
    __syncthreads();
  }
  if (tid == 0) indptr[n] = carry_s;
}

__global__ void scatter_kernel(const int* __restrict__ src, const int* __restrict__ dst,
                               int E, int gsrc_off, int slot,
                               int* __restrict__ cursor, int* __restrict__ edges){
  int i = blockIdx.x*blockDim.x + threadIdx.x;
  if (i < E) {
    int d = dst[i];
    int pos = atomicAdd(&cursor[d], 1);
    edges[pos] = (src[i] + gsrc_off) | (slot << 20);
  }
}

// ---------------------------------------------------------------------------
// Edge attention: one wave per destination node; q/k f16, v f32; fp32 math.
// agg (f16) may alias qb: each wave reads only its OWN q row first, writes
// only its own agg row last.
// ---------------------------------------------------------------------------
template<int NSLOT>
__global__ __launch_bounds__(256) void edge_attn(
    const f16* __restrict__ qb, const f16* __restrict__ kb, const float* __restrict__ vb,
    const int* __restrict__ indptr, const int* __restrict__ edges,
    const float* __restrict__ akl, const float* __restrict__ avl, const float* __restrict__ prl,
    f16* __restrict__ agg, int n_nodes, int row_off, int et0, int et1)
{
  __shared__ float AkL[NSLOT*2048];
  __shared__ float AvL[NSLOT*2048];
  const int tid = threadIdx.x;
  int etg[2] = {et0, et1};
  for (int i = tid; i < NSLOT*2048; i += 256) {
    int s = i >> 11, o = i & 2047;
    AkL[i] = akl[etg[s]*2048 + o];
    AvL[i] = avl[etg[s]*2048 + o];
  }
  __syncthreads();

  int wid = blockIdx.x*4 + (tid >> 6);
  if (wid >= n_nodes) return;
  const int lane = tid & 63;
  const int h = lane >> 3;
  const int e2 = (lane & 7)*2;
  const size_t node = (size_t)(row_off + wid);

  f16x2 q2h = *(const f16x2*)(qb + node*128 + lane*2);
  float q2x = (float)q2h[0], q2y = (float)q2h[1];

  float2 qa[NSLOT];
  #pragma unroll
  for (int s = 0; s < NSLOT; ++s) {
    const float* Ab = AkL + s*2048 + h*256;   // [d][e] 16x16
    float ax = 0.f, ay = 0.f;
    #pragma unroll
    for (int j = 0; j < 8; ++j) {
      float qx = __shfl(q2x, (h<<3)+j, 64);
      float qy = __shfl(q2y, (h<<3)+j, 64);
      ax += Ab[e2*16     + 2*j]*qx + Ab[e2*16     + 2*j+1]*qy;
      ay += Ab[(e2+1)*16 + 2*j]*qx + Ab[(e2+1)*16 + 2*j+1]*qy;
    }
    float pr = prl[etg[s]*8 + h] * 0.25f;     // p_rel * 1/sqrt(D)
    qa[s] = make_float2(ax*pr, ay*pr);
  }

  float m = -INFINITY, denom = 0.f;
  float2 acc[NSLOT];
  #pragma unroll
  for (int s = 0; s < NSLOT; ++s) acc[s] = make_float2(0.f, 0.f);

  const int beg = indptr[wid], end = indptr[wid+1];
  for (int e = beg; e < end; ++e) {
    int meta = edges[e];
    int gsrc = meta & 0xFFFFF;
    int s = meta >> 20;
    f16x2 kh = *(const f16x2*)(kb + (size_t)gsrc*128 + lane*2);
    float2 qs = (NSLOT==2 && s) ? qa[NSLOT-1] : qa[0];
    float part = qs.x*(float)kh[0] + qs.y*(float)kh[1];
    part += __shfl_xor(part, 1, 64);
    part += __shfl_xor(part, 2, 64);
    part += __shfl_xor(part, 4, 64);          // alpha for this head
    float mn = fmaxf(m, part);
    float f = expf(m - mn);                   // m=-inf first iter -> 0
    float ww = expf(part - mn);
    denom = denom*f + ww;
    float2 vv = *(const float2*)(vb + (size_t)gsrc*128 + lane*2);
    #pragma unroll
    for (int ss = 0; ss < NSLOT; ++ss) { acc[ss].x *= f; acc[ss].y *= f; }
    if (NSLOT==2 && s) { acc[NSLOT-1].x += ww*vv.x; acc[NSLOT-1].y += ww*vv.y; }
    else               { acc[0].x += ww*vv.x; acc[0].y += ww*vv.y; }
    m = mn;
  }

  float ox = 0.f, oy = 0.f;
  #pragma unroll
  for (int s = 0; s < NSLOT; ++s) {
    const float* Ab = AvL + s*2048 + h*256;   // [d][e]
    #pragma unroll
    for (int j = 0; j < 8; ++j) {
      float px = __shfl(acc[s].x, (h<<3)+j, 64);
      float py = __shfl(acc[s].y, (h<<3)+j, 64);
      ox += px*Ab[(2*j)*16 + e2]   + py*Ab[(2*j+1)*16 + e2];
      oy += px*Ab[(2*j)*16 + e2+1] + py*Ab[(2*j+1)*16 + e2+1];
    }
  }
  float dinv = 1.f/(denom + 1e-16f);
  f16x2 o; o[0] = (f16)(ox*dinv); o[1] = (f16)(oy*dinv);
  *(f16x2*)(agg + node*128 + lane*2) = o;
}

// ---------------------------------------------------------------------------
// BatchNorm on f16 h: fp32/fp64 stats, apply to f16 (hidden) or f32 (output)
// ---------------------------------------------------------------------------
__global__ __launch_bounds__(256) void bn_stats(const f16* __restrict__ h, int n,
                                                double* __restrict__ stats){
  const int c = threadIdx.x & 127, half = threadIdx.x >> 7;
  float s = 0.f, s2 = 0.f;
  for (int r = blockIdx.x*2 + half; r < n; r += gridDim.x*2) {
    float x = (float)h[(size_t)r*128 + c];
    s += x; s2 += x*x;
  }
  __shared__ float sh[2][128], sh2[2][128];
  sh[half][c] = s; sh2[half][c] = s2;
  __syncthreads();
  if (half == 0) {
    double S  = (double)s  + (double)sh[1][c];
    double S2 = (double)s2 + (double)sh2[1][c];
    atomicAdd(&stats[c], S);
    atomicAdd(&stats[128+c], S2);
  }
}

template<int OUT_F32>
__global__ __launch_bounds__(256) void bn_apply(const f16* __restrict__ h,
                                                const double* __restrict__ stats,
                                                const float* __restrict__ gamma,
                                                const float* __restrict__ beta,
                                                float* __restrict__ outf,
                                                f16* __restrict__ outh, int n){
  const int c = threadIdx.x & 127;
  double inv_n = 1.0/(double)n;
  double mu = stats[c]*inv_n;
  double var = stats[128+c]*inv_n - mu*mu;
  float scale = (float)((double)gamma[c] / sqrt(var + 1e-5));
  float shift = (float)((double)beta[c] - mu*(double)scale);
  for (int r = blockIdx.x*2 + (threadIdx.x>>7); r < n; r += gridDim.x*2) {
    float v = (float)h[(size_t)r*128 + c]*scale + shift;
    if (OUT_F32) outf[(size_t)r*128 + c] = v;
    else         outh[(size_t)r*128 + c] = (f16)v;
  }
}

// ---------------------------------------------------------------------------
extern "C" void kernel_launch(void* const* d_in, const int* in_sizes, int n_in,
                              void* d_out, int out_size, void* d_ws, size_t ws_size,
                              hipStream_t stream)
{
  const float* x_author = (const float*)d_in[0];
  const float* x_paper  = (const float*)d_in[1];
  const int* writes_src = (const int*)d_in[2];
  const int* writes_dst = (const int*)d_in[3];
  const int* rev_src    = (const int*)d_in[4];
  const int* rev_dst    = (const int*)d_in[5];
  const int* cites_src  = (const int*)d_in[6];
  const int* cites_dst  = (const int*)d_in[7];
  const float* linA_W = (const float*)d_in[8];
  const float* linA_b = (const float*)d_in[9];
  const float* linP_W = (const float*)d_in[10];
  const float* linP_b = (const float*)d_in[11];
  const float* kqv_W  = (const float*)d_in[12];
  const float* kqv_b  = (const float*)d_in[13];
  const float* a_k    = (const float*)d_in[14];
  const float* a_v    = (const float*)d_in[15];
  const float* p_rel  = (const float*)d_in[16];
  const float* out_W  = (const float*)d_in[17];
  const float* out_b  = (const float*)d_in[18];
  const float* skip   = (const float*)d_in[19];
  const float* bn_g   = (const float*)d_in[20];
  const float* bn_b   = (const float*)d_in[21];

  const size_t FEAT = (size_t)NTOT*128;

  // ws: stats(2KB) | x16 | q16(=agg16) | k16(=h16) | v32 | w16 | CSR ints
  double* stats = (double*)d_ws;
  f16* x16 = (f16*)((char*)d_ws + 2048);
  f16* q16 = x16 + FEAT;
  f16* k16 = q16 + FEAT;
  float* v32 = (float*)(k16 + FEAT);
  f16* w16 = (f16*)(v32 + FEAT);
  const int W16_TOTAL = 294912;       // 2*16384 + 4*49152 + 4*16384
  int* ibase = (int*)(w16 + W16_TOTAL);
  int* indptrA = ibase;               // NA+1
  int* cursorA = indptrA + (NA+1);    // NA
  int* degA    = cursorA + NA;        // NA
  int* indptrP = degA + NA;           // NP+1
  int* cursorP = indptrP + (NP+1);    // NP
  int* degP    = cursorP + NP;        // NP
  int* edgesA  = degP + NP;           // ER
  int* edgesP  = edgesA + ER;         // EW+EC

  size_t need = 2048 + FEAT*3*sizeof(f16) + FEAT*sizeof(float) + (size_t)W16_TOTAL*2
              + (size_t)((NA+1)+NA+NA+(NP+1)+NP+NP+ER+EW+EC)*sizeof(int);
  if (ws_size < need) {
    zero_floats<<<cdiv(out_size,256),256,0,stream>>>((float*)d_out, out_size);
    return;
  }

  // ---- weight prep: fp32 [128][N] -> fp16 [N][128] ----
  f16* linA_t = w16;                       // 16384
  f16* linP_t = w16 + 16384;               // 16384
  f16* kqv_t  = w16 + 32768;               // 4 * 49152
  f16* out_t  = w16 + 32768 + 4*49152;     // 4 * 16384
  prep_w<<<cdiv(128*128,256),256,0,stream>>>(linA_W, linA_t, 128);
  prep_w<<<cdiv(128*128,256),256,0,stream>>>(linP_W, linP_t, 128);
  for (int i = 0; i < 4; ++i) {
    prep_w<<<cdiv(128*384,256),256,0,stream>>>(kqv_W + (size_t)i*128*384, kqv_t + (size_t)i*49152, 384);
    prep_w<<<cdiv(128*128,256),256,0,stream>>>(out_W + (size_t)i*128*128, out_t + (size_t)i*16384, 128);
  }

  // ---- CSR build ----
  zero_ints<<<cdiv(NA,256),256,0,stream>>>(degA, NA);
  zero_ints<<<cdiv(NP,256),256,0,stream>>>(degP, NP);
  hist_kernel<<<cdiv(ER,256),256,0,stream>>>(rev_dst, ER, degA);
  hist_kernel<<<cdiv(EW,256),256,0,stream>>>(writes_dst, EW, degP);
  hist_kernel<<<cdiv(EC,256),256,0,stream>>>(cites_dst, EC, degP);
  scan_kernel<<<1,1024,0,stream>>>(degA, indptrA, cursorA, NA);
  scan_kernel<<<1,1024,0,stream>>>(degP, indptrP, cursorP, NP);
  scatter_kernel<<<cdiv(ER,256),256,0,stream>>>(rev_src, rev_dst, ER, NA, 0, cursorA, edgesA);
  scatter_kernel<<<cdiv(EW,256),256,0,stream>>>(writes_src, writes_dst, EW, 0, 0, cursorP, edgesP);
  scatter_kernel<<<cdiv(EC,256),256,0,stream>>>(cites_src, cites_dst, EC, NA, 1, cursorP, edgesP);

  // ---- input projections + relu (fp32 src -> x16) ----
  gemm_mfma<0><<<dim3(cdiv(NA,128),2),256,0,stream>>>(x_author, linA_t, linA_b, NA, 128,
                                                      x16, nullptr, nullptr, nullptr, nullptr);
  gemm_mfma<0><<<dim3(cdiv(NP,128),2),256,0,stream>>>(x_paper, linP_t, linP_b, NP, 128,
                                                      x16 + (size_t)NA*128, nullptr, nullptr, nullptr, nullptr);

  for (int l = 0; l < 2; ++l) {
    for (int t = 0; t < 2; ++t) {
      size_t off = t ? (size_t)NA*128 : 0;
      int M = t ? NP : NA;
      const f16* Wp = kqv_t + (size_t)(l*2+t)*49152;
      const float* bp = kqv_b + (size_t)(l*2+t)*384;
      gemm_mfma<1><<<dim3(cdiv(M,128),6),256,0,stream>>>(x16 + off, Wp, bp, M, 384,
                                                         k16 + off, q16 + off, v32 + off,
                                                         nullptr, nullptr);
    }
    const float* akl = a_k + (size_t)l*3*2048;
    const float* avl = a_v + (size_t)l*3*2048;
    const float* prl = p_rel + (size_t)l*24;
    edge_attn<1><<<NA/4,256,0,stream>>>(q16, k16, v32, indptrA, edgesA, akl, avl, prl,
                                        q16, NA, 0, 1, -1);
    edge_attn<2><<<NP/4,256,0,stream>>>(q16, k16, v32, indptrP, edgesP, akl, avl, prl,
                                        q16, NP, NA, 0, 2);

    for (int t = 0; t < 2; ++t) {
      size_t off = t ? (size_t)NA*128 : 0;
      int M = t ? NP : NA;
      f16* hbuf = k16 + off;      // k dead after edge_attn
      const f16* Wp = out_t + (size_t)(l*2+t)*16384;
      const float* bp = out_b + (size_t)(l*2+t)*128;
      gemm_mfma<2><<<dim3(cdiv(M,128),2),256,0,stream>>>(q16 + off, Wp, bp, M, 128,
                                                         hbuf, nullptr, nullptr,
                                                         x16 + off, skip + (l*2+t));
      zero_doubles<<<1,256,0,stream>>>(stats, 256);
      bn_stats<<<512,256,0,stream>>>(hbuf, M, stats);
      if (l == 0)
        bn_apply<0><<<1024,256,0,stream>>>(hbuf, stats, bn_g + l*128, bn_b + l*128,
                                           nullptr, x16 + off, M);
      else
        bn_apply<1><<<1024,256,0,stream>>>(hbuf, stats, bn_g + l*128, bn_b + l*128,
                                           (float*)d_out + off, nullptr, M);
    }
  }
}